// Round 6
// baseline (301.741 us; speedup 1.0000x reference)
//
#include <hip/hip_runtime.h>

typedef __bf16 bf16;
typedef __bf16 bf16x4 __attribute__((ext_vector_type(4)));
typedef __bf16 bf16x8 __attribute__((ext_vector_type(8)));
typedef float f32x4 __attribute__((ext_vector_type(4)));

// B_Nq = B_Ns = 16, C = 512, P = 1024, TAU*C = 256. I/O fp32; GEMMs bf16 MFMA.
// R6: barrier-free register GEMMs (no LDS) — each wave owns a 16x128 output
// tile; A/B fragments loaded straight into MFMA lane layout (bf16x8/lane).

__device__ inline float wave_reduce_sum(float v) {
#pragma unroll
    for (int m = 32; m >= 1; m >>= 1) v += __shfl_xor(v, m, 64);
    return v;
}
__device__ inline float wave_reduce_max(float v) {
#pragma unroll
    for (int m = 32; m >= 1; m >>= 1) v = fmaxf(v, __shfl_xor(v, m, 64));
    return v;
}

// K0: fused prep — fs_mean (fp32+bf16), transpose (bf16), f_q cvt to bf16.
__global__ void k_prep(const float* __restrict__ fs, const float* __restrict__ fq,
                       float* __restrict__ fsm32, bf16* __restrict__ fsm16,
                       bf16* __restrict__ fsmT, bf16* __restrict__ fq16) {
    __shared__ bf16 tile[32][33];
    int bx = blockIdx.x, by = blockIdx.y;
    int p0 = bx * 32, c0 = by * 32;
    int t = threadIdx.x, tx = t & 31, ty = t >> 5;
#pragma unroll
    for (int i = 0; i < 4; ++i) {
        size_t off = (size_t)(c0 + ty + 8 * i) * 1024 + p0 + tx;
        float s = 0.f;
#pragma unroll
        for (int b = 0; b < 16; ++b) s += fs[(size_t)b * 524288 + off];
        s *= (1.f / 16.f);
        fsm32[off] = s;
        bf16 h = (bf16)s;
        fsm16[off] = h;
        tile[ty + 8 * i][tx] = h;
    }
    __syncthreads();
#pragma unroll
    for (int i = 0; i < 4; ++i)
        fsmT[(size_t)(p0 + ty + 8 * i) * 512 + c0 + tx] = tile[tx][ty + 8 * i];
    // f_q fp32 -> bf16, 16384 floats per block
    int blk = by * 32 + bx;
    const float4* f4 = (const float4*)fq;
#pragma unroll
    for (int i = 0; i < 16; ++i) {
        int idx = blk * 4096 + i * 256 + t;  // float4 index
        float4 v = f4[idx];
        bf16x4 h4 = {(bf16)v.x, (bf16)v.y, (bf16)v.z, (bf16)v.w};
        *(bf16x4*)(fq16 + (size_t)idx * 4) = h4;
    }
}

// K1: rm[c] = rowmean(fs_mean[c,:]); u[c] = wsq[c]*wsk[c]*rm[c]/256
__global__ void k_u(const float* __restrict__ fsm32, const float* __restrict__ wsq,
                    const float* __restrict__ wsk, float* __restrict__ u,
                    float* __restrict__ rm) {
    int c = blockIdx.x;
    int t = threadIdx.x;
    float s = 0.f;
#pragma unroll
    for (int j = 0; j < 4; ++j) s += fsm32[(size_t)c * 1024 + t + 256 * j];
    s = wave_reduce_sum(s);
    __shared__ float red[4];
    int w = t >> 6, lane = t & 63;
    if (lane == 0) red[w] = s;
    __syncthreads();
    if (t == 0) {
        float rmv = (red[0] + red[1] + red[2] + red[3]) * (1.f / 1024.f);
        rm[c] = rmv;
        u[c] = wsq[c] * wsk[c] * rmv * (1.f / 256.f);
    }
}

// K2: G[b,c,d] = sum_p fq16[b,c,p]*fsm16[d,p] — barrier-free, per-wave 16x128.
// grid (4 dt, 8 ct, 16 b) = 512 blocks x 4 waves.
__global__ void k_gemm1(const bf16* __restrict__ A, const bf16* __restrict__ B,
                        float* __restrict__ G) {
    const int dt = blockIdx.x, ct = blockIdx.y, b = blockIdx.z;
    const int t = threadIdx.x, w = t >> 6, lane = t & 63;
    const int quad = lane >> 4, r15 = lane & 15;
    const bf16* ap = A + ((size_t)(b * 512 + ct * 64 + w * 16 + r15)) * 1024 + quad * 8;
    const bf16* bp = B + ((size_t)(dt * 128 + r15)) * 1024 + quad * 8;
    f32x4 acc[8] = {};
    bf16x8 a0 = *(const bf16x8*)ap;
    bf16x8 a1 = *(const bf16x8*)(ap + 32);
    bf16x8 bb[8], nb[8];
#pragma unroll
    for (int j = 0; j < 8; ++j) bb[j] = *(const bf16x8*)(bp + (size_t)j * 16384);
    for (int k0 = 0; k0 < 1024; k0 += 32) {
        int kb = (k0 + 32 <= 992) ? k0 + 32 : 992;   // clamped prefetch (no OOB)
        int ka = (k0 + 64 <= 992) ? k0 + 64 : 992;
        bf16x8 a2 = *(const bf16x8*)(ap + ka);
#pragma unroll
        for (int j = 0; j < 8; ++j) nb[j] = *(const bf16x8*)(bp + (size_t)j * 16384 + kb);
#pragma unroll
        for (int j = 0; j < 8; ++j)
            acc[j] = __builtin_amdgcn_mfma_f32_16x16x32_bf16(a0, bb[j], acc[j], 0, 0, 0);
        a0 = a1;
        a1 = a2;
#pragma unroll
        for (int j = 0; j < 8; ++j) bb[j] = nb[j];
    }
    float* g = G + ((size_t)(b * 512 + ct * 64 + w * 16 + quad * 4)) * 512 + dt * 128 + r15;
#pragma unroll
    for (int j = 0; j < 8; ++j)
#pragma unroll
        for (int ii = 0; ii < 4; ++ii)
            g[(size_t)ii * 512 + j * 16] = acc[j][ii];
}

// K3: row softmax of G*wq[c]*wk[d]/P -> Acw (folds wv); r[b,c] = sum_d Acw*rm[d]
__global__ void k_softmax_ac(const float* __restrict__ G, const float* __restrict__ wq,
                             const float* __restrict__ wk, const float* __restrict__ wv,
                             const float* __restrict__ rm, bf16* __restrict__ Acw,
                             float* __restrict__ r) {
    int row = blockIdx.x * 4 + (threadIdx.x >> 6);  // b*512 + c
    int lane = threadIdx.x & 63;
    int c = row & 511;
    const float* g = G + (size_t)row * 512;
    float sc = wq[c] * (1.f / 1024.f);
    float v[8];
    float mx = -3.4e38f;
#pragma unroll
    for (int j = 0; j < 8; ++j) {
        int d = lane + 64 * j;
        v[j] = g[d] * sc * wk[d];
        mx = fmaxf(mx, v[j]);
    }
    mx = wave_reduce_max(mx);
    float sum = 0.f;
#pragma unroll
    for (int j = 0; j < 8; ++j) {
        v[j] = __expf(v[j] - mx);
        sum += v[j];
    }
    sum = wave_reduce_sum(sum);
    float inv = 1.f / sum;
    bf16* o = Acw + (size_t)row * 512;
    float rsum = 0.f;
#pragma unroll
    for (int j = 0; j < 8; ++j) {
        int d = lane + 64 * j;
        float aw = v[j] * inv * wv[d];
        o[d] = (bf16)aw;
        rsum += aw * rm[d];
    }
    rsum = wave_reduce_sum(rsum);
    if (lane == 0) r[row] = rsum;
}

// K4: tbp[half,b,d] = sum_{c in half} u[c]*Acw[b,c,d]   (grid (2,16,2))
__global__ void k_t(const bf16* __restrict__ Acw, const float* __restrict__ u,
                    float* __restrict__ tbp) {
    int half = blockIdx.z, b = blockIdx.y;
    int d = blockIdx.x * 256 + threadIdx.x;
    const bf16* base = Acw + (size_t)b * 262144 + (size_t)half * 256 * 512 + d;
    const float* uu = u + half * 256;
    float s = 0.f;
#pragma unroll 16
    for (int c = 0; c < 256; ++c) s += uu[c] * (float)base[(size_t)c * 512];
    tbp[(half * 16 + b) * 512 + d] = s;
}

// K5: out[b,c,p] = fq + lam*sum_d Acw[b,c,d]*fsmT[p,d] — barrier-free, per-wave 16x128.
// grid (8 pt, 8 ct, 16 b) = 1024 blocks x 4 waves.
__global__ void k_gemm2(const bf16* __restrict__ A, const bf16* __restrict__ B,
                        const float* __restrict__ fq, const float* __restrict__ lamp,
                        float* __restrict__ out) {
    const int pt = blockIdx.x, ct = blockIdx.y, b = blockIdx.z;
    const int t = threadIdx.x, w = t >> 6, lane = t & 63;
    const int quad = lane >> 4, r15 = lane & 15;
    const bf16* ap = A + ((size_t)(b * 512 + ct * 64 + w * 16 + r15)) * 512 + quad * 8;
    const bf16* bp = B + ((size_t)(pt * 128 + r15)) * 512 + quad * 8;
    f32x4 acc[8] = {};
    bf16x8 a0 = *(const bf16x8*)ap;
    bf16x8 a1 = *(const bf16x8*)(ap + 32);
    bf16x8 bb[8], nb[8];
#pragma unroll
    for (int j = 0; j < 8; ++j) bb[j] = *(const bf16x8*)(bp + (size_t)j * 8192);
    for (int k0 = 0; k0 < 512; k0 += 32) {
        int kb = (k0 + 32 <= 480) ? k0 + 32 : 480;
        int ka = (k0 + 64 <= 480) ? k0 + 64 : 480;
        bf16x8 a2 = *(const bf16x8*)(ap + ka);
#pragma unroll
        for (int j = 0; j < 8; ++j) nb[j] = *(const bf16x8*)(bp + (size_t)j * 8192 + kb);
#pragma unroll
        for (int j = 0; j < 8; ++j)
            acc[j] = __builtin_amdgcn_mfma_f32_16x16x32_bf16(a0, bb[j], acc[j], 0, 0, 0);
        a0 = a1;
        a1 = a2;
#pragma unroll
        for (int j = 0; j < 8; ++j) bb[j] = nb[j];
    }
    float lam = lamp[0];
    size_t rowbase = (size_t)(b * 512 + ct * 64 + w * 16 + quad * 4);
#pragma unroll
    for (int j = 0; j < 8; ++j)
#pragma unroll
        for (int ii = 0; ii < 4; ++ii) {
            size_t idx = (rowbase + ii) * 1024 + pt * 128 + j * 16 + r15;
            out[idx] = fq[idx] + lam * acc[j][ii];
        }
}

// K6: z<16: alog[b,p] = sum_d (tbp0+tbp1)[b,d]*fsm[d,p]; z>=16: blog via r
__global__ void k_logits(const float* __restrict__ tbp, const float* __restrict__ r,
                         const float* __restrict__ wsq, const float* __restrict__ wsk,
                         const float* __restrict__ fsm32, float* __restrict__ alog,
                         float* __restrict__ blog) {
    int z = blockIdx.y, pq = blockIdx.x * 256 + threadIdx.x;
    if (z < 16) {
        const float* t0 = tbp + z * 512;
        const float* t1 = tbp + (16 + z) * 512;
        float s = 0.f;
#pragma unroll 8
        for (int d = 0; d < 512; ++d) s += (t0[d] + t1[d]) * fsm32[(size_t)d * 1024 + pq];
        alog[z * 1024 + pq] = s;
    } else {
        int b = z - 16;
        float s = 0.f;
#pragma unroll 8
        for (int c = 0; c < 512; ++c) {
            float coef = r[b * 512 + c] * wsq[c] * wsk[c] * (1.f / 256.f);
            s += coef * fsm32[(size_t)c * 1024 + pq];
        }
        blog[b * 1024 + pq] = s;
    }
}

// K7: z<16: alpha softmax -> out; z>=16: beta softmax -> ws
__global__ void k_softmax_rows(const float* __restrict__ alog, const float* __restrict__ blog,
                               float* __restrict__ alpha_out, float* __restrict__ beta) {
    int z = blockIdx.x;
    int t = threadIdx.x;
    int w = t >> 6, lane = t & 63;
    const float* src = (z < 16) ? (alog + (size_t)z * 1024) : (blog + (size_t)(z - 16) * 1024);
    float v[4];
    float mx = -3.4e38f;
#pragma unroll
    for (int j = 0; j < 4; ++j) {
        v[j] = src[t + 256 * j];
        mx = fmaxf(mx, v[j]);
    }
    __shared__ float red[4];
    float wm = wave_reduce_max(mx);
    if (lane == 0) red[w] = wm;
    __syncthreads();
    mx = fmaxf(fmaxf(red[0], red[1]), fmaxf(red[2], red[3]));
    float s = 0.f;
#pragma unroll
    for (int j = 0; j < 4; ++j) {
        v[j] = __expf(v[j] - mx);
        s += v[j];
    }
    __syncthreads();
    float ws_ = wave_reduce_sum(s);
    if (lane == 0) red[w] = ws_;
    __syncthreads();
    s = red[0] + red[1] + red[2] + red[3];
    float inv = 1.f / s;
    if (z < 16) {
#pragma unroll
        for (int j = 0; j < 4; ++j) alpha_out[(size_t)z * 1024 + t + 256 * j] = v[j] * inv;
    } else {
#pragma unroll
        for (int j = 0; j < 4; ++j) beta[(size_t)(z - 16) * 1024 + t + 256 * j] = v[j] * inv;
    }
}

// K8: beta_mean broadcast
__global__ void k_betamean(const float* __restrict__ beta, float* __restrict__ out) {
    int q = blockIdx.x * 256 + threadIdx.x;
    float s = 0.f;
#pragma unroll
    for (int b = 0; b < 16; ++b) s += beta[b * 1024 + q];
    float val = s * (1.f / 16.f);
#pragma unroll
    for (int si = 0; si < 16; ++si) out[(size_t)si * 1024 + q] = val;
}

extern "C" void kernel_launch(void* const* d_in, const int* in_sizes, int n_in,
                              void* d_out, int out_size, void* d_ws, size_t ws_size,
                              hipStream_t stream) {
    const float* f_q = (const float*)d_in[0];
    const float* f_s = (const float*)d_in[1];
    const float* w_cca_q = (const float*)d_in[2];
    const float* w_cca_k = (const float*)d_in[3];
    const float* w_cca_v = (const float*)d_in[4];
    const float* w_sca_q = (const float*)d_in[5];
    const float* w_sca_k = (const float*)d_in[6];
    const float* lamp = (const float*)d_in[7];

    char* ws = (char*)d_ws;
    float* fsm32 = (float*)(ws + 0);             //  2 MB   [512,1024]
    bf16* fsm16 = (bf16*)(ws + 2097152);         //  1 MB
    bf16* fsmT = (bf16*)(ws + 3145728);          //  1 MB   [1024,512]
    float* G = (float*)(ws + 4194304);           // 16 MB   [16,512,512]
    bf16* Acw = (bf16*)(ws + 20971520);          //  8 MB   [16,512,512]
    bf16* fq16 = (bf16*)(ws + 29360128);         // 16.8 MB [16,512,1024]
    float* rm = (float*)(ws + 46137344);         //  2 KB
    float* u = (float*)(ws + 46139392);          //  2 KB
    float* r = (float*)(ws + 46141440);          // 32 KB   [16,512]
    float* tbp = (float*)(ws + 46174208);        // 64 KB   [32,512]
    float* alog = (float*)(ws + 46239744);       // 64 KB
    float* blog = (float*)(ws + 46305280);       // 64 KB
    float* beta = (float*)(ws + 46370816);       // 64 KB

    float* out_fq = (float*)d_out;
    float* out_alpha = out_fq + 8388608;
    float* out_bmean = out_fq + 8404992;

    k_prep<<<dim3(32, 16), 256, 0, stream>>>(f_s, f_q, fsm32, fsm16, fsmT, fq16);
    k_u<<<512, 256, 0, stream>>>(fsm32, w_sca_q, w_sca_k, u, rm);
    k_gemm1<<<dim3(4, 8, 16), 256, 0, stream>>>(fq16, fsm16, G);
    k_softmax_ac<<<2048, 256, 0, stream>>>(G, w_cca_q, w_cca_k, w_cca_v, rm, Acw, r);
    k_t<<<dim3(2, 16, 2), 256, 0, stream>>>(Acw, u, tbp);
    k_gemm2<<<dim3(8, 8, 16), 256, 0, stream>>>(Acw, fsmT, f_q, lamp, out_fq);
    k_logits<<<dim3(4, 32), 256, 0, stream>>>(tbp, r, w_sca_q, w_sca_k, fsm32, alog, blog);
    k_softmax_rows<<<32, 256, 0, stream>>>(alog, blog, out_alpha, beta);
    k_betamean<<<4, 256, 0, stream>>>(beta, out_bmean);
}

// Round 7
// 211.774 us; speedup vs baseline: 1.4248x; 1.4248x over previous
//
#include <hip/hip_runtime.h>

typedef __bf16 bf16;
typedef __bf16 bf16x4 __attribute__((ext_vector_type(4)));
typedef __bf16 bf16x8 __attribute__((ext_vector_type(8)));
typedef float f32x4 __attribute__((ext_vector_type(4)));

// B_Nq = B_Ns = 16, C = 512, P = 1024, TAU*C = 256. I/O fp32; GEMMs bf16 MFMA.
// R7: GLL16 + XOR-swizzled LDS (2-way max conflicts) + single-barrier double
// buffer; 64x64 tiles, gemm1 4 blocks/CU, gemm2 8 blocks/CU.

#define GLL16(g, l)                                                             \
    __builtin_amdgcn_global_load_lds((const __attribute__((address_space(1))) void*)(g), \
                                     (__attribute__((address_space(3))) void*)(l), 16, 0, 0)

__device__ inline float wave_reduce_sum(float v) {
#pragma unroll
    for (int m = 32; m >= 1; m >>= 1) v += __shfl_xor(v, m, 64);
    return v;
}
__device__ inline float wave_reduce_max(float v) {
#pragma unroll
    for (int m = 32; m >= 1; m >>= 1) v = fmaxf(v, __shfl_xor(v, m, 64));
    return v;
}

// K0: fused prep — fs_mean (fp32+bf16), transpose (bf16), f_q cvt to bf16.
__global__ void k_prep(const float* __restrict__ fs, const float* __restrict__ fq,
                       float* __restrict__ fsm32, bf16* __restrict__ fsm16,
                       bf16* __restrict__ fsmT, bf16* __restrict__ fq16) {
    __shared__ bf16 tile[32][33];
    int bx = blockIdx.x, by = blockIdx.y;
    int p0 = bx * 32, c0 = by * 32;
    int t = threadIdx.x, tx = t & 31, ty = t >> 5;
#pragma unroll
    for (int i = 0; i < 4; ++i) {
        size_t off = (size_t)(c0 + ty + 8 * i) * 1024 + p0 + tx;
        float s = 0.f;
#pragma unroll
        for (int b = 0; b < 16; ++b) s += fs[(size_t)b * 524288 + off];
        s *= (1.f / 16.f);
        fsm32[off] = s;
        bf16 h = (bf16)s;
        fsm16[off] = h;
        tile[ty + 8 * i][tx] = h;
    }
    __syncthreads();
#pragma unroll
    for (int i = 0; i < 4; ++i)
        fsmT[(size_t)(p0 + ty + 8 * i) * 512 + c0 + tx] = tile[tx][ty + 8 * i];
    int blk = by * 32 + bx;
    const float4* f4 = (const float4*)fq;
#pragma unroll
    for (int i = 0; i < 16; ++i) {
        int idx = blk * 4096 + i * 256 + t;
        float4 v = f4[idx];
        bf16x4 h4 = {(bf16)v.x, (bf16)v.y, (bf16)v.z, (bf16)v.w};
        *(bf16x4*)(fq16 + (size_t)idx * 4) = h4;
    }
}

// K1: rm[c] = rowmean(fs_mean[c,:]); u[c] = wsq[c]*wsk[c]*rm[c]/256
__global__ void k_u(const float* __restrict__ fsm32, const float* __restrict__ wsq,
                    const float* __restrict__ wsk, float* __restrict__ u,
                    float* __restrict__ rm) {
    int c = blockIdx.x;
    int t = threadIdx.x;
    float s = 0.f;
#pragma unroll
    for (int j = 0; j < 4; ++j) s += fsm32[(size_t)c * 1024 + t + 256 * j];
    s = wave_reduce_sum(s);
    __shared__ float red[4];
    int w = t >> 6, lane = t & 63;
    if (lane == 0) red[w] = s;
    __syncthreads();
    if (t == 0) {
        float rmv = (red[0] + red[1] + red[2] + red[3]) * (1.f / 1024.f);
        rm[c] = rmv;
        u[c] = wsq[c] * wsk[c] * rmv * (1.f / 256.f);
    }
}

// K2: G[b,c,d] = sum_p fq16[b,c,p]*fsm16[d,p] — 64x64 tile, BK=32, K=1024.
// XOR-swizzled LDS + single-barrier dbuf. grid (8 dt, 8 ct, 16 b) = 1024 blocks.
__global__ void k_gemm1(const bf16* __restrict__ A, const bf16* __restrict__ B,
                        float* __restrict__ G) {
    __shared__ alignas(16) bf16 As[2][64 * 32];
    __shared__ alignas(16) bf16 Bs[2][64 * 32];
    const int dt = blockIdx.x, ct = blockIdx.y, b = blockIdx.z;
    const int t = threadIdx.x, w = t >> 6, lane = t & 63;
    const int quad = lane >> 4, r15 = lane & 15;
    const bf16* Abase = A + ((size_t)(b * 512 + ct * 64)) * 1024;
    const bf16* Bbase = B + ((size_t)(dt * 64)) * 1024;
    const int sr = t >> 2;                              // staging row 0..63
    const int gc = ((t & 3) ^ ((sr >> 1) & 3)) * 8;     // swizzled global chunk
    const int rsel = (quad ^ ((r15 >> 1) & 3)) * 8;     // read-side chunk
    f32x4 acc[4] = {};
    GLL16(Abase + (size_t)sr * 1024 + gc, As[0] + t * 8);
    GLL16(Bbase + (size_t)sr * 1024 + gc, Bs[0] + t * 8);
    int cur = 0;
    for (int k0 = 0; k0 < 1024; k0 += 32) {
        __syncthreads();
        if (k0 + 32 < 1024) {
            GLL16(Abase + (size_t)sr * 1024 + k0 + 32 + gc, As[cur ^ 1] + t * 8);
            GLL16(Bbase + (size_t)sr * 1024 + k0 + 32 + gc, Bs[cur ^ 1] + t * 8);
        }
        bf16x8 af = *(const bf16x8*)(As[cur] + (w * 16 + r15) * 32 + rsel);
#pragma unroll
        for (int j = 0; j < 4; ++j) {
            bf16x8 bfr = *(const bf16x8*)(Bs[cur] + (j * 16 + r15) * 32 + rsel);
            acc[j] = __builtin_amdgcn_mfma_f32_16x16x32_bf16(af, bfr, acc[j], 0, 0, 0);
        }
        cur ^= 1;
    }
    float* g = G + ((size_t)(b * 512 + ct * 64 + w * 16 + quad * 4)) * 512 + dt * 64 + r15;
#pragma unroll
    for (int j = 0; j < 4; ++j)
#pragma unroll
        for (int ii = 0; ii < 4; ++ii)
            g[(size_t)ii * 512 + j * 16] = acc[j][ii];
}

// K3: row softmax of G*wq[c]*wk[d]/P -> Acw (folds wv); r[b,c] = sum_d Acw*rm[d]
__global__ void k_softmax_ac(const float* __restrict__ G, const float* __restrict__ wq,
                             const float* __restrict__ wk, const float* __restrict__ wv,
                             const float* __restrict__ rm, bf16* __restrict__ Acw,
                             float* __restrict__ r) {
    int row = blockIdx.x * 4 + (threadIdx.x >> 6);  // b*512 + c
    int lane = threadIdx.x & 63;
    int c = row & 511;
    const float* g = G + (size_t)row * 512;
    float sc = wq[c] * (1.f / 1024.f);
    float v[8];
    float mx = -3.4e38f;
#pragma unroll
    for (int j = 0; j < 8; ++j) {
        int d = lane + 64 * j;
        v[j] = g[d] * sc * wk[d];
        mx = fmaxf(mx, v[j]);
    }
    mx = wave_reduce_max(mx);
    float sum = 0.f;
#pragma unroll
    for (int j = 0; j < 8; ++j) {
        v[j] = __expf(v[j] - mx);
        sum += v[j];
    }
    sum = wave_reduce_sum(sum);
    float inv = 1.f / sum;
    bf16* o = Acw + (size_t)row * 512;
    float rsum = 0.f;
#pragma unroll
    for (int j = 0; j < 8; ++j) {
        int d = lane + 64 * j;
        float aw = v[j] * inv * wv[d];
        o[d] = (bf16)aw;
        rsum += aw * rm[d];
    }
    rsum = wave_reduce_sum(rsum);
    if (lane == 0) r[row] = rsum;
}

// K4: tbp[q,b,d] = sum_{c in quarter q} u[c]*Acw[b,c,d]   (grid (2,16,4))
__global__ void k_t(const bf16* __restrict__ Acw, const float* __restrict__ u,
                    float* __restrict__ tbp) {
    int q = blockIdx.z, b = blockIdx.y;
    int d = blockIdx.x * 256 + threadIdx.x;
    const bf16* base = Acw + (size_t)b * 262144 + (size_t)q * 128 * 512 + d;
    const float* uu = u + q * 128;
    float s = 0.f;
#pragma unroll 16
    for (int c = 0; c < 128; ++c) s += uu[c] * (float)base[(size_t)c * 512];
    tbp[(q * 16 + b) * 512 + d] = s;
}

// K5: out[b,c,p] = fq + lam*sum_d Acw[b,c,d]*fsmT[p,d] — 64x64 tile, K=512.
// grid (16 pt, 8 ct, 16 b) = 2048 blocks.
__global__ void k_gemm2(const bf16* __restrict__ A, const bf16* __restrict__ B,
                        const float* __restrict__ fq, const float* __restrict__ lamp,
                        float* __restrict__ out) {
    __shared__ alignas(16) bf16 As[2][64 * 32];
    __shared__ alignas(16) bf16 Bs[2][64 * 32];
    const int pt = blockIdx.x, ct = blockIdx.y, b = blockIdx.z;
    const int t = threadIdx.x, w = t >> 6, lane = t & 63;
    const int quad = lane >> 4, r15 = lane & 15;
    const bf16* Abase = A + ((size_t)(b * 512 + ct * 64)) * 512;
    const bf16* Bbase = B + ((size_t)(pt * 64)) * 512;
    const int sr = t >> 2;
    const int gc = ((t & 3) ^ ((sr >> 1) & 3)) * 8;
    const int rsel = (quad ^ ((r15 >> 1) & 3)) * 8;
    f32x4 acc[4] = {};
    GLL16(Abase + (size_t)sr * 512 + gc, As[0] + t * 8);
    GLL16(Bbase + (size_t)sr * 512 + gc, Bs[0] + t * 8);
    int cur = 0;
    for (int k0 = 0; k0 < 512; k0 += 32) {
        __syncthreads();
        if (k0 + 32 < 512) {
            GLL16(Abase + (size_t)sr * 512 + k0 + 32 + gc, As[cur ^ 1] + t * 8);
            GLL16(Bbase + (size_t)sr * 512 + k0 + 32 + gc, Bs[cur ^ 1] + t * 8);
        }
        bf16x8 af = *(const bf16x8*)(As[cur] + (w * 16 + r15) * 32 + rsel);
#pragma unroll
        for (int j = 0; j < 4; ++j) {
            bf16x8 bfr = *(const bf16x8*)(Bs[cur] + (j * 16 + r15) * 32 + rsel);
            acc[j] = __builtin_amdgcn_mfma_f32_16x16x32_bf16(af, bfr, acc[j], 0, 0, 0);
        }
        cur ^= 1;
    }
    float lam = lamp[0];
    size_t rowbase = (size_t)(b * 512 + ct * 64 + w * 16 + quad * 4);
#pragma unroll
    for (int j = 0; j < 4; ++j)
#pragma unroll
        for (int ii = 0; ii < 4; ++ii) {
            size_t idx = (rowbase + ii) * 1024 + pt * 64 + j * 16 + r15;
            out[idx] = fq[idx] + lam * acc[j][ii];
        }
}

// K6: z<16: alog[b,p] = sum_d (Σq tbp[q])[b,d]*fsm[d,p]; z>=16: blog via r
__global__ void k_logits(const float* __restrict__ tbp, const float* __restrict__ r,
                         const float* __restrict__ wsq, const float* __restrict__ wsk,
                         const float* __restrict__ fsm32, float* __restrict__ alog,
                         float* __restrict__ blog) {
    int z = blockIdx.y, pq = blockIdx.x * 256 + threadIdx.x;
    if (z < 16) {
        const float* t0 = tbp + z * 512;
        float s = 0.f;
#pragma unroll 8
        for (int d = 0; d < 512; ++d) {
            float tv = t0[d] + t0[8192 + d] + t0[16384 + d] + t0[24576 + d];
            s += tv * fsm32[(size_t)d * 1024 + pq];
        }
        alog[z * 1024 + pq] = s;
    } else {
        int b = z - 16;
        float s = 0.f;
#pragma unroll 8
        for (int c = 0; c < 512; ++c) {
            float coef = r[b * 512 + c] * wsq[c] * wsk[c] * (1.f / 256.f);
            s += coef * fsm32[(size_t)c * 1024 + pq];
        }
        blog[b * 1024 + pq] = s;
    }
}

// K7: z<16: alpha softmax -> out; z>=16: beta softmax -> ws
__global__ void k_softmax_rows(const float* __restrict__ alog, const float* __restrict__ blog,
                               float* __restrict__ alpha_out, float* __restrict__ beta) {
    int z = blockIdx.x;
    int t = threadIdx.x;
    int w = t >> 6, lane = t & 63;
    const float* src = (z < 16) ? (alog + (size_t)z * 1024) : (blog + (size_t)(z - 16) * 1024);
    float v[4];
    float mx = -3.4e38f;
#pragma unroll
    for (int j = 0; j < 4; ++j) {
        v[j] = src[t + 256 * j];
        mx = fmaxf(mx, v[j]);
    }
    __shared__ float red[4];
    float wm = wave_reduce_max(mx);
    if (lane == 0) red[w] = wm;
    __syncthreads();
    mx = fmaxf(fmaxf(red[0], red[1]), fmaxf(red[2], red[3]));
    float s = 0.f;
#pragma unroll
    for (int j = 0; j < 4; ++j) {
        v[j] = __expf(v[j] - mx);
        s += v[j];
    }
    __syncthreads();
    float ws_ = wave_reduce_sum(s);
    if (lane == 0) red[w] = ws_;
    __syncthreads();
    s = red[0] + red[1] + red[2] + red[3];
    float inv = 1.f / s;
    if (z < 16) {
#pragma unroll
        for (int j = 0; j < 4; ++j) alpha_out[(size_t)z * 1024 + t + 256 * j] = v[j] * inv;
    } else {
#pragma unroll
        for (int j = 0; j < 4; ++j) beta[(size_t)(z - 16) * 1024 + t + 256 * j] = v[j] * inv;
    }
}

// K8: beta_mean broadcast
__global__ void k_betamean(const float* __restrict__ beta, float* __restrict__ out) {
    int q = blockIdx.x * 256 + threadIdx.x;
    float s = 0.f;
#pragma unroll
    for (int b = 0; b < 16; ++b) s += beta[b * 1024 + q];
    float val = s * (1.f / 16.f);
#pragma unroll
    for (int si = 0; si < 16; ++si) out[(size_t)si * 1024 + q] = val;
}

extern "C" void kernel_launch(void* const* d_in, const int* in_sizes, int n_in,
                              void* d_out, int out_size, void* d_ws, size_t ws_size,
                              hipStream_t stream) {
    const float* f_q = (const float*)d_in[0];
    const float* f_s = (const float*)d_in[1];
    const float* w_cca_q = (const float*)d_in[2];
    const float* w_cca_k = (const float*)d_in[3];
    const float* w_cca_v = (const float*)d_in[4];
    const float* w_sca_q = (const float*)d_in[5];
    const float* w_sca_k = (const float*)d_in[6];
    const float* lamp = (const float*)d_in[7];

    char* ws = (char*)d_ws;
    float* fsm32 = (float*)(ws + 0);             //  2 MB   [512,1024]
    bf16* fsm16 = (bf16*)(ws + 2097152);         //  1 MB
    bf16* fsmT = (bf16*)(ws + 3145728);          //  1 MB   [1024,512]
    float* G = (float*)(ws + 4194304);           // 16 MB   [16,512,512]
    bf16* Acw = (bf16*)(ws + 20971520);          //  8 MB   [16,512,512]
    bf16* fq16 = (bf16*)(ws + 29360128);         // 16.8 MB [16,512,1024]
    float* rm = (float*)(ws + 46137344);         //  2 KB
    float* u = (float*)(ws + 46139392);          //  2 KB
    float* r = (float*)(ws + 46141440);          // 32 KB   [16,512]
    float* tbp = (float*)(ws + 46174208);        // 128 KB  [64,512]
    float* alog = (float*)(ws + 46305280);       // 64 KB
    float* blog = (float*)(ws + 46370816);       // 64 KB
    float* beta = (float*)(ws + 46436352);       // 64 KB

    float* out_fq = (float*)d_out;
    float* out_alpha = out_fq + 8388608;
    float* out_bmean = out_fq + 8404992;

    k_prep<<<dim3(32, 16), 256, 0, stream>>>(f_s, f_q, fsm32, fsm16, fsmT, fq16);
    k_u<<<512, 256, 0, stream>>>(fsm32, w_sca_q, w_sca_k, u, rm);
    k_gemm1<<<dim3(8, 8, 16), 256, 0, stream>>>(fq16, fsm16, G);
    k_softmax_ac<<<2048, 256, 0, stream>>>(G, w_cca_q, w_cca_k, w_cca_v, rm, Acw, r);
    k_t<<<dim3(2, 16, 4), 256, 0, stream>>>(Acw, u, tbp);
    k_gemm2<<<dim3(16, 8, 16), 256, 0, stream>>>(Acw, fsmT, f_q, lamp, out_fq);
    k_logits<<<dim3(4, 32), 256, 0, stream>>>(tbp, r, w_sca_q, w_sca_k, fsm32, alog, blog);
    k_softmax_rows<<<32, 256, 0, stream>>>(alog, blog, out_alpha, beta);
    k_betamean<<<4, 256, 0, stream>>>(beta, out_bmean);
}

// Round 9
// 207.387 us; speedup vs baseline: 1.4550x; 1.0212x over previous
//
#include <hip/hip_runtime.h>

typedef __bf16 bf16;
typedef __bf16 bf16x4 __attribute__((ext_vector_type(4)));
typedef __bf16 bf16x8 __attribute__((ext_vector_type(8)));
typedef float f32x4 __attribute__((ext_vector_type(4)));

// B_Nq = B_Ns = 16, C = 512, P = 1024, TAU*C = 256. I/O fp32; GEMMs bf16 MFMA.
// R9: R4-proven GEMM path (output 0) + safe fusions only:
//   - k_u folded into k_prep (raw row-sum atomics; scales applied inline)
//   - logits+softmax fused (32 x 1024 thr, R5-proven logic)

#define GLL16(g, l)                                                             \
    __builtin_amdgcn_global_load_lds((const __attribute__((address_space(1))) void*)(g), \
                                     (__attribute__((address_space(3))) void*)(l), 16, 0, 0)

__device__ inline float wave_reduce_sum(float v) {
#pragma unroll
    for (int m = 32; m >= 1; m >>= 1) v += __shfl_xor(v, m, 64);
    return v;
}
__device__ inline float wave_reduce_max(float v) {
#pragma unroll
    for (int m = 32; m >= 1; m >>= 1) v = fmaxf(v, __shfl_xor(v, m, 64));
    return v;
}

// K0: prep — fs_mean (fp32+bf16+transposed), f_q cvt, rm[c] raw row-sum atomics.
__global__ void k_prep(const float* __restrict__ fs, const float* __restrict__ fq,
                       float* __restrict__ fsm32, bf16* __restrict__ fsm16,
                       bf16* __restrict__ fsmT, bf16* __restrict__ fq16,
                       float* __restrict__ rm) {
    __shared__ bf16 tile[32][33];
    int bx = blockIdx.x, by = blockIdx.y;
    int p0 = bx * 32, c0 = by * 32;
    int t = threadIdx.x, tx = t & 31, ty = t >> 5;
    float rs[4];
#pragma unroll
    for (int i = 0; i < 4; ++i) {
        size_t off = (size_t)(c0 + ty + 8 * i) * 1024 + p0 + tx;
        float s = 0.f;
#pragma unroll
        for (int b = 0; b < 16; ++b) s += fs[(size_t)b * 524288 + off];
        s *= (1.f / 16.f);
        fsm32[off] = s;
        bf16 h = (bf16)s;
        fsm16[off] = h;
        tile[ty + 8 * i][tx] = h;
        rs[i] = s;
    }
    // per-row partial sums over this block's 32 p's (reduce over tx bits 0..4)
#pragma unroll
    for (int i = 0; i < 4; ++i) {
        float v = rs[i];
#pragma unroll
        for (int m = 16; m >= 1; m >>= 1) v += __shfl_xor(v, m, 64);
        if (tx == 0) atomicAdd(&rm[c0 + ty + 8 * i], v);
    }
    __syncthreads();
#pragma unroll
    for (int i = 0; i < 4; ++i)
        fsmT[(size_t)(p0 + ty + 8 * i) * 512 + c0 + tx] = tile[tx][ty + 8 * i];
    int blk = by * 32 + bx;
    const float4* f4 = (const float4*)fq;
#pragma unroll
    for (int i = 0; i < 16; ++i) {
        int idx = blk * 4096 + i * 256 + t;
        float4 v = f4[idx];
        bf16x4 h4 = {(bf16)v.x, (bf16)v.y, (bf16)v.z, (bf16)v.w};
        *(bf16x4*)(fq16 + (size_t)idx * 4) = h4;
    }
}

// K1: G[b,c,d] = sum_p fq16[b,c,p]*fsm16[d,p] — 64(c)x128(d) tile, K=1024 (R4-proven).
__global__ void k_gemm1(const bf16* __restrict__ A, const bf16* __restrict__ B,
                        float* __restrict__ G) {
    __shared__ alignas(16) bf16 As[64 * 32];
    __shared__ alignas(16) bf16 Bs[128 * 32];
    const int dt = blockIdx.x, ct = blockIdx.y, b = blockIdx.z;
    const int t = threadIdx.x, w = t >> 6, lane = t & 63;
    const int quad = lane >> 4, r15 = lane & 15;
    const bf16* Abase = A + ((size_t)(b * 512 + ct * 64)) * 1024;
    const bf16* Bbase = B + ((size_t)(dt * 128)) * 1024;
    const int sr = t >> 2, sc = (t & 3) * 8;
    f32x4 acc[8] = {};
    for (int k0 = 0; k0 < 1024; k0 += 32) {
        GLL16(Abase + (size_t)sr * 1024 + k0 + sc, As + t * 8);
        GLL16(Bbase + (size_t)sr * 1024 + k0 + sc, Bs + t * 8);
        GLL16(Bbase + (size_t)(sr + 64) * 1024 + k0 + sc, Bs + (t + 256) * 8);
        __syncthreads();
        bf16x8 af = *(const bf16x8*)(As + (w * 16 + r15) * 32 + quad * 8);
#pragma unroll
        for (int j = 0; j < 8; ++j) {
            bf16x8 bfr = *(const bf16x8*)(Bs + (j * 16 + r15) * 32 + quad * 8);
            acc[j] = __builtin_amdgcn_mfma_f32_16x16x32_bf16(af, bfr, acc[j], 0, 0, 0);
        }
        __syncthreads();
    }
    float* g = G + ((size_t)(b * 512 + ct * 64 + w * 16 + quad * 4)) * 512 + dt * 128 + r15;
#pragma unroll
    for (int j = 0; j < 8; ++j)
#pragma unroll
        for (int ii = 0; ii < 4; ++ii)
            g[(size_t)ii * 512 + j * 16] = acc[j][ii];
}

// K2: row softmax of G*wq[c]*wk[d]/P -> Acw (folds wv); r[b,c] = sum_d Acw*rm[d]/1024
__global__ void k_softmax_ac(const float* __restrict__ G, const float* __restrict__ wq,
                             const float* __restrict__ wk, const float* __restrict__ wv,
                             const float* __restrict__ rm, bf16* __restrict__ Acw,
                             float* __restrict__ r) {
    int row = blockIdx.x * 4 + (threadIdx.x >> 6);  // b*512 + c
    int lane = threadIdx.x & 63;
    int c = row & 511;
    const float* g = G + (size_t)row * 512;
    float sc = wq[c] * (1.f / 1024.f);
    float v[8];
    float mx = -3.4e38f;
#pragma unroll
    for (int j = 0; j < 8; ++j) {
        int d = lane + 64 * j;
        v[j] = g[d] * sc * wk[d];
        mx = fmaxf(mx, v[j]);
    }
    mx = wave_reduce_max(mx);
    float sum = 0.f;
#pragma unroll
    for (int j = 0; j < 8; ++j) {
        v[j] = __expf(v[j] - mx);
        sum += v[j];
    }
    sum = wave_reduce_sum(sum);
    float inv = 1.f / sum;
    bf16* o = Acw + (size_t)row * 512;
    float rsum = 0.f;
#pragma unroll
    for (int j = 0; j < 8; ++j) {
        int d = lane + 64 * j;
        float aw = v[j] * inv * wv[d];
        o[d] = (bf16)aw;
        rsum += aw * rm[d] * (1.f / 1024.f);  // rm is raw row-sum
    }
    rsum = wave_reduce_sum(rsum);
    if (lane == 0) r[row] = rsum;
}

// K3: out[b,c,p] = fq + lam*sum_d Acw[b,c,d]*fsmT[p,d] — 64x128 tile, K=512 (R4-proven).
__global__ void k_gemm2(const bf16* __restrict__ A, const bf16* __restrict__ B,
                        const float* __restrict__ fq, const float* __restrict__ lamp,
                        float* __restrict__ out) {
    __shared__ alignas(16) bf16 As[64 * 32];
    __shared__ alignas(16) bf16 Bs[128 * 32];
    const int pt = blockIdx.x, ct = blockIdx.y, b = blockIdx.z;
    const int t = threadIdx.x, w = t >> 6, lane = t & 63;
    const int quad = lane >> 4, r15 = lane & 15;
    const bf16* Abase = A + ((size_t)(b * 512 + ct * 64)) * 512;
    const bf16* Bbase = B + ((size_t)(pt * 128)) * 512;
    const int sr = t >> 2, sc = (t & 3) * 8;
    f32x4 acc[8] = {};
    for (int k0 = 0; k0 < 512; k0 += 32) {
        GLL16(Abase + (size_t)sr * 512 + k0 + sc, As + t * 8);
        GLL16(Bbase + (size_t)sr * 512 + k0 + sc, Bs + t * 8);
        GLL16(Bbase + (size_t)(sr + 64) * 512 + k0 + sc, Bs + (t + 256) * 8);
        __syncthreads();
        bf16x8 af = *(const bf16x8*)(As + (w * 16 + r15) * 32 + quad * 8);
#pragma unroll
        for (int j = 0; j < 8; ++j) {
            bf16x8 bfr = *(const bf16x8*)(Bs + (j * 16 + r15) * 32 + quad * 8);
            acc[j] = __builtin_amdgcn_mfma_f32_16x16x32_bf16(af, bfr, acc[j], 0, 0, 0);
        }
        __syncthreads();
    }
    float lam = lamp[0];
    size_t rowbase = (size_t)(b * 512 + ct * 64 + w * 16 + quad * 4);
#pragma unroll
    for (int j = 0; j < 8; ++j)
#pragma unroll
        for (int ii = 0; ii < 4; ++ii) {
            size_t idx = (rowbase + ii) * 1024 + pt * 128 + j * 16 + r15;
            out[idx] = fq[idx] + lam * acc[j][ii];
        }
}

// K4: tbp[q,b,d] = sum_{c in quarter q} u[c]*Acw[b,c,d]; u computed inline from rm.
__global__ void k_t(const bf16* __restrict__ Acw, const float* __restrict__ rm,
                    const float* __restrict__ wsq, const float* __restrict__ wsk,
                    float* __restrict__ tbp) {
    __shared__ float u_sh[128];
    int q = blockIdx.z, b = blockIdx.y;
    int d = blockIdx.x * 256 + threadIdx.x;
    if (threadIdx.x < 128) {
        int c = q * 128 + threadIdx.x;
        u_sh[threadIdx.x] = rm[c] * wsq[c] * wsk[c] * (1.f / 262144.f);  // /(1024*256)
    }
    __syncthreads();
    const bf16* base = Acw + (size_t)b * 262144 + (size_t)q * 128 * 512 + d;
    float s = 0.f;
#pragma unroll 16
    for (int c = 0; c < 128; ++c) s += u_sh[c] * (float)base[(size_t)c * 512];
    tbp[(q * 16 + b) * 512 + d] = s;
}

// K5: fused logits + softmax. 32 blocks x 1024 threads (one p per thread).
// z<16: alpha row -> out; z>=16: beta row -> ws.
__global__ __launch_bounds__(1024) void k_logsoft(
    const float* __restrict__ tbp, const float* __restrict__ r,
    const float* __restrict__ wsq, const float* __restrict__ wsk,
    const float* __restrict__ fsm32, float* __restrict__ alpha_out,
    float* __restrict__ beta) {
    __shared__ float coef[512];
    __shared__ float red[16];
    int z = blockIdx.x, t = threadIdx.x, w = t >> 6, lane = t & 63;
    if (t < 512) {
        if (z < 16)
            coef[t] = tbp[z * 512 + t] + tbp[(16 + z) * 512 + t] +
                      tbp[(32 + z) * 512 + t] + tbp[(48 + z) * 512 + t];
        else
            coef[t] = r[(z - 16) * 512 + t] * wsq[t] * wsk[t] * (1.f / 256.f);
    }
    __syncthreads();
    float s = 0.f;
#pragma unroll 8
    for (int d = 0; d < 512; ++d) s = fmaf(coef[d], fsm32[(size_t)d * 1024 + t], s);
    float mx = s;
#pragma unroll
    for (int m = 32; m >= 1; m >>= 1) mx = fmaxf(mx, __shfl_xor(mx, m, 64));
    if (lane == 0) red[w] = mx;
    __syncthreads();
    float m2 = red[0];
#pragma unroll
    for (int i = 1; i < 16; ++i) m2 = fmaxf(m2, red[i]);
    __syncthreads();
    float e = __expf(s - m2);
    float ss = wave_reduce_sum(e);
    if (lane == 0) red[w] = ss;
    __syncthreads();
    float tot = 0.f;
#pragma unroll
    for (int i = 0; i < 16; ++i) tot += red[i];
    float val = e / tot;
    if (z < 16) alpha_out[(size_t)z * 1024 + t] = val;
    else beta[(size_t)(z - 16) * 1024 + t] = val;
}

// K6: beta_mean broadcast
__global__ void k_betamean(const float* __restrict__ beta, float* __restrict__ out) {
    int q = blockIdx.x * 256 + threadIdx.x;
    float s = 0.f;
#pragma unroll
    for (int b = 0; b < 16; ++b) s += beta[b * 1024 + q];
    float val = s * (1.f / 16.f);
#pragma unroll
    for (int si = 0; si < 16; ++si) out[(size_t)si * 1024 + q] = val;
}

extern "C" void kernel_launch(void* const* d_in, const int* in_sizes, int n_in,
                              void* d_out, int out_size, void* d_ws, size_t ws_size,
                              hipStream_t stream) {
    const float* f_q = (const float*)d_in[0];
    const float* f_s = (const float*)d_in[1];
    const float* w_cca_q = (const float*)d_in[2];
    const float* w_cca_k = (const float*)d_in[3];
    const float* w_cca_v = (const float*)d_in[4];
    const float* w_sca_q = (const float*)d_in[5];
    const float* w_sca_k = (const float*)d_in[6];
    const float* lamp = (const float*)d_in[7];

    char* ws = (char*)d_ws;
    float* fsm32 = (float*)(ws + 0);             //  2 MB   [512,1024]
    bf16* fsm16 = (bf16*)(ws + 2097152);         //  1 MB
    bf16* fsmT = (bf16*)(ws + 3145728);          //  1 MB   [1024,512]
    bf16* fq16 = (bf16*)(ws + 4194304);          // 16.8 MB [16,512,1024]
    float* G = (float*)(ws + 20971520);          // 16 MB   [16,512,512]
    bf16* Acw = (bf16*)(ws + 37748736);          //  8 MB   [16,512,512]
    float* rm = (float*)(ws + 46137344);         //  2 KB   raw row sums
    float* tbp = (float*)(ws + 46139392);        // 128 KB  [64,512]
    float* r = (float*)(ws + 46270464);          // 32 KB   [16,512]
    float* beta = (float*)(ws + 46303232);       // 64 KB

    float* out_fq = (float*)d_out;
    float* out_alpha = out_fq + 8388608;
    float* out_bmean = out_fq + 8404992;

    hipMemsetAsync(ws + 46137344, 0, 133120, stream);  // rm + tbp
    k_prep<<<dim3(32, 16), 256, 0, stream>>>(f_s, f_q, fsm32, fsm16, fsmT, fq16, rm);
    k_gemm1<<<dim3(4, 8, 16), 256, 0, stream>>>(fq16, fsm16, G);
    k_softmax_ac<<<2048, 256, 0, stream>>>(G, w_cca_q, w_cca_k, w_cca_v, rm, Acw, r);
    k_gemm2<<<dim3(8, 8, 16), 256, 0, stream>>>(Acw, fsmT, f_q, lamp, out_fq);
    k_t<<<dim3(2, 16, 4), 256, 0, stream>>>(Acw, rm, w_sca_q, w_sca_k, tbp);
    k_logsoft<<<32, 1024, 0, stream>>>(tbp, r, w_sca_q, w_sca_k, fsm32, out_alpha, beta);
    k_betamean<<<4, 256, 0, stream>>>(beta, out_bmean);
}